// Round 7
// baseline (946.475 us; speedup 1.0000x reference)
//
#include <hip/hip_runtime.h>
#include <hip/hip_fp16.h>
#include <math.h>

// SpinSphericalBlock: separable spin-weighted SHT -> channel mix -> inverse SHT
// -> complex BN (spin0 mean, via Parseval on G) -> magnitude-ReLU gating.
//
// Constants: B=8, RES=64, RES_OUT=32, L=15, SPINS_IN=(0,1), SPINS_OUT=(0,1,2),
// C_IN=64, C_OUT=128, NM=31. Output: out_size=3,145,728 float32 = Re(y),
// (b,t,p,s,d) row-major (established R0-R4).
//
// R23 post-mortem of R22: launch_bounds(512,4) squeezed VGPR to 64 -> spill
// (WRITE 43->75MB, VALUBusy 17->9.8, mega 285->475us) even though occupancy
// hit 47%. Occupancy theory still live; implementation poisoned it. Fix:
// demand occupancy via GRID, not allocator pressure:
//   * 1024 blocks x 256 thr = 4 blk/CU = 16 waves/CU (4x R21 latency hiding).
//   * launch_bounds(256,4): cap 128 >= R21's observed 96 -> no spill, and
//     guarantees >=4 blk/CU residency for the manual barrier (actual 96 VGPR
//     gives capacity 5 -> margin). LDS 20KB x4 = 80 <= 160KB.
//   * P5 keeps R22's LDS phasor table (no st[31] in regs).
// All phase index mappings are re-hostings of R22's correctness-verified ones.
//
//   P1: W-pack + Wigner tables (fp64) + stats zero + phi-DFT -> F
//       (DFT: 1024 blk = (bt 512, m-half 2), 8 m/thread)
//   P2: theta-in: 496 blk (mi,b,i), 4 t-groups, tree reduce (verbatim R21)
//   P3: mix: 1024 blk = (bq 2, b-pair 2, k 256), 192 thr, 2 b/thread
//   P4: theta-out+stats: 992 blk = (mi,b,t-half,sd-half), 192 thr
//   P5: synth+BN+gate: 1024 blk = (bt 256, p-half 2, sd-half 2), 192 thr

#define PI_D 3.14159265358979323846

// ---------------- workspace layout (bytes) ----------------
#define OFF_A_IN    ((size_t)24320)     // 2*256*64 float    = 131072
#define OFF_A_OUT   ((size_t)155648)    // 3*256*32 float    = 98304
#define OFF_STATS   ((size_t)254208)    // 3*384 float       = 4608
#define OFF_BAR     ((size_t)259072)    // grid-barrier counter (64 B)
#define OFF_R1      ((size_t)260608)    // F fp16 (8.1MB) then oc fp16 (3.1MB)
#define OFF_R2      ((size_t)25426688)  // coeffs fp16 (1MB) then G fp16 (12.2MB)
#define OFF_W       ((size_t)67108864)  // packed weights float4 (6.3MB)

// ln(j!) for j=0..30
__constant__ double LF[31] = {
    0.0, 0.0, 0.6931471805599453, 1.791759469228055, 3.1780538303479458,
    4.787491742782046, 6.579251212010101, 8.525161361065415,
    10.604602902745251, 12.801827480081469, 15.104412573075516,
    17.502307845873887, 19.987214495661885, 22.552163853123425,
    25.19122118273868, 27.89927138384089, 30.671860106080672,
    33.50507345013689, 36.39544520803305, 39.339884187199495,
    42.335616460753485, 45.38013889847691, 48.47118135183523,
    51.60667556776438, 54.78472939811232, 58.00360522298052,
    61.261701761002, 64.55753862700634, 67.88974313718154,
    71.25703896716801, 74.65823634883016};

__device__ inline int isqrt_k(int k) {
    int l = (int)sqrtf((float)k + 0.5f);
    while (l * l > k) --l;
    while ((l + 1) * (l + 1) <= k) ++l;
    return l;
}

// d^l_{m,n}(theta) via seed term (1 exp + 2 log) + exact ratio recurrence.
__device__ double wigner_d_rec(int l, int m, int n, double theta) {
    int an = n < 0 ? -n : n;
    int am = m < 0 ? -m : m;
    if (l < an || l < am) return 0.0;
    int kmin = max(0, n - m), kmax = min(l + n, l - m);
    if (kmax < kmin) return 0.0;
    double cb = cos(0.5 * theta), sb = sin(0.5 * theta);
    double pref = 0.5 * (LF[l + m] + LF[l - m] + LF[l + n] + LF[l - n]);
    double lterm = pref
        - (LF[l + n - kmin] + LF[kmin] + LF[m - n + kmin] + LF[l - m - kmin])
        + (double)(2 * l + n - m - 2 * kmin) * log(cb)
        + (double)(m - n + 2 * kmin) * log(sb);
    double term = exp(lterm);
    if ((m - n + kmin) & 1) term = -term;
    double r = (sb * sb) / (cb * cb);
    double acc = term;
    for (int k = kmin; k < kmax; ++k) {
        term *= -((double)((l + n - k) * (l - m - k)) * r)
                / ((double)((k + 1) * (m - n + k + 1)));
        acc += term;
    }
    return acc;
}

// Manual grid barrier (proven R21). Counter zeroed by host memset each launch.
__device__ __forceinline__ void gbar(unsigned* bar, unsigned target) {
    __syncthreads();
    if (threadIdx.x == 0) {
        __threadfence();  // release: publish this block's stores
        __hip_atomic_fetch_add(bar, 1u, __ATOMIC_RELEASE,
                               __HIP_MEMORY_SCOPE_AGENT);
        unsigned tries = 0;
        while (__hip_atomic_load(bar, __ATOMIC_ACQUIRE,
                                 __HIP_MEMORY_SCOPE_AGENT) < target) {
            __builtin_amdgcn_s_sleep(2);
            if (++tries > 200000u) break;  // ~10 ms bound, fails loudly
        }
        __threadfence();  // acquire: drop stale lines
    }
    __syncthreads();
}

__global__ __launch_bounds__(256, 4) void k_mega(
    const float* __restrict__ xr, const float* __restrict__ xi,
    const float* __restrict__ kr, const float* __restrict__ ki,
    const float* __restrict__ gamma, const float* __restrict__ betar,
    const float* __restrict__ betai, const float* __restrict__ bias,
    float* __restrict__ out,
    float* __restrict__ A_in, float* __restrict__ A_out,
    float* __restrict__ stats,
    __half2* __restrict__ F, __half2* __restrict__ coeffs,
    __half2* __restrict__ oc, __half2* __restrict__ G,
    float4* __restrict__ W, unsigned* __restrict__ bar) {
    __shared__ union {
        struct { float A[16][64]; float2 red[2][16][64]; } p2;  // 20 KB
        struct { float2 cs[2][128]; } p3;                       // 2 KB
        struct { float Ao[3][16][32]; } p4;                     // 6 KB
        struct { float2 tab[8][31]; } p5;                       // 2 KB
    } sm;

    float* ssr = stats;
    float* ssi = stats + 384;
    float* ssq = stats + 768;

    int bid = blockIdx.x, tid = threadIdx.x;
    int gidx = bid * 256 + tid;   // 0..262143

    // ================= P1: W-pack + tables + stats zero + phi-DFT =========
    {
        const float2* kr2 = (const float2*)kr;
        const float2* ki2 = (const float2*)ki;
#pragma unroll
        for (int j = 0; j < 2; ++j) {
            int e = gidx + j * 262144;   // 393216 float4 total
            if (e < 393216) {
                int dp = e & 63, r = e >> 6; // r = lis*64+u < 6144
                float2 a = kr2[(size_t)r * 64 + dp];
                float2 b = ki2[(size_t)r * 64 + dp];
                W[e] = make_float4(a.x, a.y, b.x, b.y);
            }
        }
        if (gidx < 32768) {
            int idx = gidx;
            int t = idx & 63, k = (idx >> 6) & 255, i = idx >> 14;
            int l = isqrt_k(k);
            int m = k - l * l - l;
            double theta = ((double)t + 0.5) * PI_D / 64.0;
            double w = sin(theta) * (PI_D / 64.0) * (2.0 * PI_D / 64.0);
            double norm = sqrt((2.0 * l + 1.0) / (4.0 * PI_D));
            double d = wigner_d_rec(l, m, -i, theta);
            A_in[idx] = (float)(((m & 1) ? -1.0 : 1.0) * norm * w * d);
        } else if (gidx < 57344) {
            int idx = gidx - 32768;
            int t = idx & 31, k = (idx >> 5) & 255, s = idx >> 13;
            int l = isqrt_k(k);
            int m = k - l * l - l;
            double theta = ((double)t + 0.5) * PI_D / 32.0;
            double norm = sqrt((2.0 * l + 1.0) / (4.0 * PI_D));
            double d = wigner_d_rec(l, m, -s, theta);
            A_out[idx] = (float)(((m & 1) ? -1.0 : 1.0) * norm * d);
        } else if (gidx < 58496) {
            stats[gidx - 57344] = 0.f;
        }
    }
    // ---- phi-DFT: (bt 512, m-half 2) blocks; 8 m's per thread ----
    {
        int bt = bid >> 1, h = bid & 1;
        int iu = tid & 127, mh_loc = tid >> 7;     // 0..1
        int mi0 = (h * 2 + mh_loc) * 8;            // multiples of 8
        float2 acc[8], w[8], st[8];
#pragma unroll
        for (int j = 0; j < 8; ++j) {
            int m = mi0 + j - 15;
            float sy, sx;
            __sincosf(-(float)m * (float)(PI_D / 32.0), &sy, &sx);
            st[j] = make_float2(sx, sy);
            w[j] = make_float2(1.f, 0.f);
            acc[j] = make_float2(0.f, 0.f);
        }
        const float* xrb = xr + (size_t)bt * 8192 + iu;
        const float* xib = xi + (size_t)bt * 8192 + iu;
        for (int p = 0; p < 32; ++p) {
            float a  = xrb[(size_t)p * 128];
            float b  = xib[(size_t)p * 128];
            float a2 = xrb[(size_t)(p + 32) * 128];
            float b2 = xib[(size_t)(p + 32) * 128];
            float sar = a + a2, sai = b + b2;   // even m
            float dar = a - a2, dai = b - b2;   // odd m
#pragma unroll
            for (int j = 0; j < 8; ++j) {
                float ur = (j & 1) ? sar : dar;  // j odd -> m even
                float ui = (j & 1) ? sai : dai;
                acc[j].x += ur * w[j].x - ui * w[j].y;
                acc[j].y += ur * w[j].y + ui * w[j].x;
                float nx = w[j].x * st[j].x - w[j].y * st[j].y;
                w[j].y = w[j].x * st[j].y + w[j].y * st[j].x;
                w[j].x = nx;
            }
        }
        __half2* Fb = F + (size_t)bt * 31 * 128 + iu;
#pragma unroll
        for (int j = 0; j < 8; ++j) {
            int mi = mi0 + j;
            if (mi < 31) Fb[(size_t)mi * 128] = __float22half2_rn(acc[j]);
        }
    }
    gbar(bar, 1024);

    // ================= P2: theta-in contraction (verbatim R21) =============
    if (bid < 496) {
        int mi = bid % 31;
        int q = bid / 31;
        int b = q >> 1, z = q & 1;  // z = i
        int m = mi - 15;
        int am = m < 0 ? -m : m;
        for (int idx = tid; idx < 1024; idx += 256) {
            int j = idx >> 6, t = idx & 63;
            float v = 0.f;
            if (j >= am) v = A_in[((size_t)z * 256 + (j * j + j + m)) * 64 + t];
            sm.p2.A[j][t] = v;
        }
        __syncthreads();
        int iu_l = tid & 63, th = tid >> 6;
        int iu = z * 64 + iu_l;
        float2 acc[16];
#pragma unroll
        for (int j = 0; j < 16; ++j) acc[j] = make_float2(0.f, 0.f);
        const __half2* Fb = F + ((size_t)b * 64 * 31 + mi) * 128 + iu;
        for (int tt = 0; tt < 16; ++tt) {
            int t = th * 16 + tt;
            float2 f = __half22float2(Fb[(size_t)t * 31 * 128]);
#pragma unroll
            for (int j = 0; j < 16; ++j) {
                float a = sm.p2.A[j][t];
                acc[j].x += a * f.x;
                acc[j].y += a * f.y;
            }
        }
        if (th >= 2) {
#pragma unroll
            for (int j = 0; j < 16; ++j) sm.p2.red[th - 2][j][iu_l] = acc[j];
        }
        __syncthreads();
        if (th < 2) {
#pragma unroll
            for (int j = 0; j < 16; ++j) {
                float2 r = sm.p2.red[th][j][iu_l];
                acc[j].x += r.x;
                acc[j].y += r.y;
            }
        }
        __syncthreads();
        if (th == 1) {
#pragma unroll
            for (int j = 0; j < 16; ++j) sm.p2.red[0][j][iu_l] = acc[j];
        }
        __syncthreads();
        if (th == 0) {
#pragma unroll
            for (int j = 0; j < 16; ++j) {
                if (j >= am) {
                    float2 r = sm.p2.red[0][j][iu_l];
                    coeffs[((size_t)b * 256 + (j * j + j + m)) * 128 + iu] =
                        __float22half2_rn(
                            make_float2(acc[j].x + r.x, acc[j].y + r.y));
                }
            }
        }
    }
    gbar(bar, 2048);

    // ================= P3: channel mix =====================================
    // 1024 blocks = (bq 2, b-pair 2, k 256); 192 active = (s 3, dp 64).
    {
        int y = bid >> 9;                  // bq
        int bh = (bid >> 8) & 1;           // which b-pair
        int bxk = bid & 255;
        int k = ((bxk & 7) << 5) + (bxk >> 3);  // XCD-chunked k
        int b0 = y * 4 + bh * 2;
        for (int idx = tid; idx < 256; idx += 256) {
            int bb = idx >> 7, iuu = idx & 127;
            sm.p3.cs[bb][iuu] =
                __half22float2(coeffs[((size_t)(b0 + bb) * 256 + k) * 128 + iuu]);
        }
        __syncthreads();
        if (tid < 192) {
            int s = tid >> 6, dp = tid & 63;
            int l = isqrt_k(k);
            float2 acc[2][2];
#pragma unroll
            for (int bb = 0; bb < 2; ++bb) {
                acc[bb][0] = make_float2(0.f, 0.f);
                acc[bb][1] = make_float2(0.f, 0.f);
            }
            const float4* W0 = W + (size_t)(6 * l + s) * 4096 + dp;  // i=0
            const float4* W1 = W0 + (size_t)3 * 4096;                // i=1
            float4 cur[4];
#pragma unroll
            for (int j = 0; j < 4; ++j) cur[j] = W0[(size_t)j * 64];
            for (int g = 0; g < 32; ++g) {
                float4 nxt[4];
                if (g < 31) {
                    int iu0 = (g + 1) * 4;
                    const float4* P = (iu0 < 64) ? (W0 + (size_t)iu0 * 64)
                                                 : (W1 + (size_t)(iu0 - 64) * 64);
#pragma unroll
                    for (int j = 0; j < 4; ++j) nxt[j] = P[(size_t)j * 64];
                }
#pragma unroll
                for (int j = 0; j < 4; ++j) {
                    int iu = g * 4 + j;
                    float2 wr = make_float2(cur[j].x, cur[j].y);
                    float2 wi = make_float2(cur[j].z, cur[j].w);
#pragma unroll
                    for (int bb = 0; bb < 2; ++bb) {
                        float2 cv = sm.p3.cs[bb][iu];
                        acc[bb][0].x += cv.x * wr.x - cv.y * wi.x;
                        acc[bb][0].y += cv.x * wi.x + cv.y * wr.x;
                        acc[bb][1].x += cv.x * wr.y - cv.y * wi.y;
                        acc[bb][1].y += cv.x * wi.y + cv.y * wr.y;
                    }
                }
                if (g < 31) {
#pragma unroll
                    for (int j = 0; j < 4; ++j) cur[j] = nxt[j];
                }
            }
#pragma unroll
            for (int bb = 0; bb < 2; ++bb) {
                size_t o = ((size_t)(b0 + bb) * 256 + k) * 384 + s * 128 + 2 * dp;
                oc[o]     = __float22half2_rn(acc[bb][0]);
                oc[o + 1] = __float22half2_rn(acc[bb][1]);
            }
        }
    }
    gbar(bar, 3072);

    // ================= P4: theta expansion + G store + stats ===============
    // 992 blocks = (mi 31, b 8, t-half 2, sd-half 2); 192 active = sd.
    if (bid < 992) {
        int mi = bid % 31;
        int q = bid / 31;            // 0..31
        int b = q >> 2;
        int thalf = (q >> 1) & 1;
        int shalf = q & 1;
        int m = mi - 15;
        int am = m < 0 ? -m : m;
        for (int idx = tid; idx < 1536; idx += 256) {
            int s = idx >> 9, j = (idx >> 5) & 15, t = idx & 31;
            float v = 0.f;
            if (j >= am) v = A_out[((size_t)s * 256 + (j * j + j + m)) * 32 + t];
            sm.p4.Ao[s][j][t] = v;
        }
        __syncthreads();
        if (tid < 192) {
            int sd = shalf * 192 + tid;
            int s = sd >> 7;
            float2 c[16];
#pragma unroll
            for (int j = 0; j < 16; ++j) {
                c[j] = make_float2(0.f, 0.f);
                if (j >= am)
                    c[j] = __half22float2(
                        oc[((size_t)b * 256 + (j * j + j + m)) * 384 + sd]);
            }
            float sq = 0.f, sr = 0.f, si = 0.f;
            int t0 = thalf * 16;
            for (int t = t0; t < t0 + 16; ++t) {
                float fr = 0.f, fi = 0.f;
#pragma unroll
                for (int j = 0; j < 16; ++j) {
                    float a = sm.p4.Ao[s][j][t];
                    fr += a * c[j].x;
                    fi += a * c[j].y;
                }
                G[(((size_t)b * 32 + t) * 31 + mi) * 384 + sd] =
                    __float22half2_rn(make_float2(fr, fi));
                sq += fr * fr + fi * fi;
                if (mi == 15) { sr += fr; si += fi; }
            }
            atomicAdd(&ssq[sd], sq);
            if (mi == 15) {
                atomicAdd(&ssr[sd], sr);
                atomicAdd(&ssi[sd], si);
            }
        }
    }
    gbar(bar, 4096);

    // ================= P5: phi synthesis + BN + gate =======================
    // 1024 blocks = (bt 256, p-half 2, sd-half 2); 192 active = sd.
    // LDS phasor table tab[p_loc][mi] = e^{i m (phalf*8+p_loc) pi/16}.
    {
        int bt = bid >> 2;
        int phalf = (bid >> 1) & 1;
        int shalf = bid & 1;
        if (tid < 248) {
            int p_loc = tid / 31, mi = tid % 31;
            float sy, sx;
            __sincosf((float)(mi - 15) * (float)(phalf * 8 + p_loc)
                          * (float)(PI_D / 16.0), &sy, &sx);
            sm.p5.tab[p_loc][mi] = make_float2(sx, sy);
        }
        __syncthreads();
        if (tid < 192) {
            int sd = shalf * 192 + tid;
            int s = sd >> 7;
            float2 g[31];
#pragma unroll
            for (int mi = 0; mi < 31; ++mi)
                g[mi] = __half22float2(G[((size_t)bt * 31 + mi) * 384 + sd]);
            const float invN = 1.0f / 256.0f;
            float mur = 0.f, mui = 0.f;
            if (s == 0) { mur = ssr[sd] * invN; mui = ssi[sd] * invN; }
            float var = ssq[sd] * invN - (mur * mur + mui * mui);
            float scale = gamma[sd] / sqrtf(var + 1e-5f);
            float br = (s == 0) ? betar[sd] : 0.f;
            float bi = (s == 0) ? betai[sd] : 0.f;
            float bb = bias[sd];
            float* ob = out + (size_t)bt * 32 * 384 + sd;
            for (int p_loc = 0; p_loc < 8; ++p_loc) {
                int p = phalf * 8 + p_loc;
                float fr = 0.f, fi = 0.f, fr2 = 0.f, fi2 = 0.f;
#pragma unroll
                for (int mi = 0; mi < 31; ++mi) {
                    float2 ph = sm.p5.tab[p_loc][mi];
                    float tr = g[mi].x * ph.x - g[mi].y * ph.y;
                    float ti = g[mi].x * ph.y + g[mi].y * ph.x;
                    fr += tr;
                    fi += ti;
                    if (mi & 1) { fr2 += tr; fi2 += ti; }  // m even
                    else        { fr2 -= tr; fi2 -= ti; }  // m odd
                }
                {
                    float yr = (fr - mur) * scale + br;
                    float yi = (fi - mui) * scale + bi;
                    float mag = sqrtf(yr * yr + yi * yi);
                    float f = fmaxf(mag + bb, 0.f) / (mag + 1e-6f);
                    ob[(size_t)p * 384] = yr * f;
                }
                {
                    float yr = (fr2 - mur) * scale + br;
                    float yi = (fi2 - mui) * scale + bi;
                    float mag = sqrtf(yr * yr + yi * yi);
                    float f = fmaxf(mag + bb, 0.f) / (mag + 1e-6f);
                    ob[(size_t)(p + 16) * 384] = yr * f;
                }
            }
        }
    }
}

extern "C" void kernel_launch(void* const* d_in, const int* in_sizes, int n_in,
                              void* d_out, int out_size, void* d_ws, size_t ws_size,
                              hipStream_t stream) {
    const float* xr    = (const float*)d_in[0];
    const float* xi    = (const float*)d_in[1];
    const float* kr    = (const float*)d_in[2];
    const float* ki    = (const float*)d_in[3];
    const float* gamma = (const float*)d_in[4];
    const float* betar = (const float*)d_in[5];
    const float* betai = (const float*)d_in[6];
    const float* bias  = (const float*)d_in[7];
    float* out = (float*)d_out;

    char* ws = (char*)d_ws;
    float*   A_in   = (float*)(ws + OFF_A_IN);
    float*   A_out  = (float*)(ws + OFF_A_OUT);
    float*   stats  = (float*)(ws + OFF_STATS);
    unsigned* bar   = (unsigned*)(ws + OFF_BAR);
    __half2* F      = (__half2*)(ws + OFF_R1);  // aliased: oc after P2
    __half2* oc     = (__half2*)(ws + OFF_R1);
    __half2* coeffs = (__half2*)(ws + OFF_R2);  // aliased: G after P3
    __half2* G      = (__half2*)(ws + OFF_R2);
    float4*  W      = (float4*)(ws + OFF_W);

    hipMemsetAsync(ws + OFF_BAR, 0, 64, stream);  // zero barrier counter
    k_mega<<<1024, 256, 0, stream>>>(xr, xi, kr, ki, gamma, betar, betai, bias,
                                     out, A_in, A_out, stats, F, coeffs, oc, G,
                                     W, bar);
}

// Round 10
// 449.051 us; speedup vs baseline: 2.1077x; 2.1077x over previous
//
#include <hip/hip_runtime.h>
#include <hip/hip_fp16.h>
#include <math.h>

// SpinSphericalBlock: separable spin-weighted SHT -> channel mix -> inverse SHT
// -> complex BN (spin0 mean, via Parseval on G) -> magnitude-ReLU gating.
//
// Constants: B=8, RES=64, RES_OUT=32, L=15, SPINS_IN=(0,1), SPINS_OUT=(0,1,2),
// C_IN=64, C_OUT=128, NM=31. Output: out_size=3,145,728 float32 = Re(y),
// (b,t,p,s,d) row-major (established R0-R4).
//
// R26 post-mortem of R24/R25: both failed the residency gamble (sync-garbage
// ssq blowup) even when margin arithmetic said safe -> allocator VGPR choice
// is unpredictable; ANY design needing k>1 blocks/CU resident is gambling.
// Only reliable config: grid <= 256, 1 block/CU (R21 proved it; only flaw was
// 4 waves/CU). Fix: 256 blocks x 768 THREADS = 12 waves/CU (3x R21 hiding).
//   * launch_bounds(768): compiler MUST cap VGPR<=170 for launchability;
//     natural ~96 << 170 -> no spill, no squeeze. If it launches, all 256
//     blocks are resident (capacity >= 1 per CU at t=0) -> barrier safe
//     STRUCTURALLY, not probabilistically.
//   * Each block = 3 virtual 256-thread blocks (vb = bid*3 + tid/256);
//     LDS partitioned x3 (P2: 60KB); __syncthreads kept block-uniform
//     (work guarded by act, barriers unconditional; block skips keyed on bid).
// Phase math verbatim R23/R25 (correctness-proven at R23).
//
//   P1: W-pack + Wigner tables (fp64) + stats zero + phi-DFT -> F
//   P2: theta-in: 496 virtual units (mi,b,i)
//   P3: mix: 1024 virtual units (bq 2, b-pair 2, k 256), 2 rounds
//   P4: theta-out+stats: 992 virtual units, 2 rounds
//   P5: synth+BN+gate: 1024 virtual units, 2 rounds

#define PI_D 3.14159265358979323846

// ---------------- workspace layout (bytes) ----------------
#define OFF_A_IN    ((size_t)24320)     // 2*256*64 float    = 131072
#define OFF_A_OUT   ((size_t)155648)    // 3*256*32 float    = 98304
#define OFF_STATS   ((size_t)254208)    // 3*384 float       = 4608
#define OFF_BAR     ((size_t)259072)    // grid-barrier counter (64 B)
#define OFF_R1      ((size_t)260608)    // F fp16 (8.1MB) then oc fp16 (3.1MB)
#define OFF_R2      ((size_t)25426688)  // coeffs fp16 (1MB) then G fp16 (12.2MB)
#define OFF_W       ((size_t)67108864)  // packed weights float4 (6.3MB)

// ln(j!) for j=0..30
__constant__ double LF[31] = {
    0.0, 0.0, 0.6931471805599453, 1.791759469228055, 3.1780538303479458,
    4.787491742782046, 6.579251212010101, 8.525161361065415,
    10.604602902745251, 12.801827480081469, 15.104412573075516,
    17.502307845873887, 19.987214495661885, 22.552163853123425,
    25.19122118273868, 27.89927138384089, 30.671860106080672,
    33.50507345013689, 36.39544520803305, 39.339884187199495,
    42.335616460753485, 45.38013889847691, 48.47118135183523,
    51.60667556776438, 54.78472939811232, 58.00360522298052,
    61.261701761002, 64.55753862700634, 67.88974313718154,
    71.25703896716801, 74.65823634883016};

__device__ inline int isqrt_k(int k) {
    int l = (int)sqrtf((float)k + 0.5f);
    while (l * l > k) --l;
    while ((l + 1) * (l + 1) <= k) ++l;
    return l;
}

// d^l_{m,n}(theta) via seed term (1 exp + 2 log) + exact ratio recurrence.
__device__ double wigner_d_rec(int l, int m, int n, double theta) {
    int an = n < 0 ? -n : n;
    int am = m < 0 ? -m : m;
    if (l < an || l < am) return 0.0;
    int kmin = max(0, n - m), kmax = min(l + n, l - m);
    if (kmax < kmin) return 0.0;
    double cb = cos(0.5 * theta), sb = sin(0.5 * theta);
    double pref = 0.5 * (LF[l + m] + LF[l - m] + LF[l + n] + LF[l - n]);
    double lterm = pref
        - (LF[l + n - kmin] + LF[kmin] + LF[m - n + kmin] + LF[l - m - kmin])
        + (double)(2 * l + n - m - 2 * kmin) * log(cb)
        + (double)(m - n + 2 * kmin) * log(sb);
    double term = exp(lterm);
    if ((m - n + kmin) & 1) term = -term;
    double r = (sb * sb) / (cb * cb);
    double acc = term;
    for (int k = kmin; k < kmax; ++k) {
        term *= -((double)((l + n - k) * (l - m - k)) * r)
                / ((double)((k + 1) * (m - n + k + 1)));
        acc += term;
    }
    return acc;
}

// Manual grid barrier (proven R21). Counter zeroed by host memset each launch.
__device__ __forceinline__ void gbar(unsigned* bar, unsigned target) {
    __syncthreads();
    if (threadIdx.x == 0) {
        __threadfence();  // release: publish this block's stores
        __hip_atomic_fetch_add(bar, 1u, __ATOMIC_RELEASE,
                               __HIP_MEMORY_SCOPE_AGENT);
        unsigned tries = 0;
        while (__hip_atomic_load(bar, __ATOMIC_ACQUIRE,
                                 __HIP_MEMORY_SCOPE_AGENT) < target) {
            __builtin_amdgcn_s_sleep(2);
            if (++tries > 200000u) break;  // ~10 ms bound, fails loudly
        }
        __threadfence();  // acquire: drop stale lines
    }
    __syncthreads();
}

__global__ __launch_bounds__(768) void k_mega(
    const float* __restrict__ xr, const float* __restrict__ xi,
    const float* __restrict__ kr, const float* __restrict__ ki,
    const float* __restrict__ gamma, const float* __restrict__ betar,
    const float* __restrict__ betai, const float* __restrict__ bias,
    float* __restrict__ out,
    float* __restrict__ A_in, float* __restrict__ A_out,
    float* __restrict__ stats,
    __half2* __restrict__ F, __half2* __restrict__ coeffs,
    __half2* __restrict__ oc, __half2* __restrict__ G,
    float4* __restrict__ W, unsigned* __restrict__ bar) {
    __shared__ union {
        struct { float A[3][16][64]; float2 red[3][2][16][64]; } p2;  // 60 KB
        struct { float2 cs[3][2][128]; } p3;                          // 3 KB
        struct { float Ao[3][3][16][32]; } p4;                        // 18 KB
        struct { float2 tab[3][8][31]; } p5;                          // 6 KB
    } sm;

    float* ssr = stats;
    float* ssi = stats + 384;
    float* ssq = stats + 768;

    int bid = blockIdx.x, tid = threadIdx.x;
    int g = tid >> 8;          // virtual-block group 0..2
    int tv = tid & 255;        // virtual tid
    int vb = bid * 3 + g;      // virtual block 0..767
    int gidx = bid * 768 + tid;  // 0..196607

    // ================= P1: W-pack + tables + stats zero + phi-DFT =========
    {
        const float2* kr2 = (const float2*)kr;
        const float2* ki2 = (const float2*)ki;
#pragma unroll
        for (int j = 0; j < 2; ++j) {
            int e = gidx + j * 196608;   // 2*196608 = 393216 float4 exactly
            int dp = e & 63, r = e >> 6; // r = lis*64+u < 6144
            float2 a = kr2[(size_t)r * 64 + dp];
            float2 b = ki2[(size_t)r * 64 + dp];
            W[e] = make_float4(a.x, a.y, b.x, b.y);
        }
        if (gidx < 32768) {
            int idx = gidx;
            int t = idx & 63, k = (idx >> 6) & 255, i = idx >> 14;
            int l = isqrt_k(k);
            int m = k - l * l - l;
            double theta = ((double)t + 0.5) * PI_D / 64.0;
            double w = sin(theta) * (PI_D / 64.0) * (2.0 * PI_D / 64.0);
            double norm = sqrt((2.0 * l + 1.0) / (4.0 * PI_D));
            double d = wigner_d_rec(l, m, -i, theta);
            A_in[idx] = (float)(((m & 1) ? -1.0 : 1.0) * norm * w * d);
        } else if (gidx < 57344) {
            int idx = gidx - 32768;
            int t = idx & 31, k = (idx >> 5) & 255, s = idx >> 13;
            int l = isqrt_k(k);
            int m = k - l * l - l;
            double theta = ((double)t + 0.5) * PI_D / 32.0;
            double norm = sqrt((2.0 * l + 1.0) / (4.0 * PI_D));
            double d = wigner_d_rec(l, m, -s, theta);
            A_out[idx] = (float)(((m & 1) ? -1.0 : 1.0) * norm * d);
        } else if (gidx < 58496) {
            stats[gidx - 57344] = 0.f;
        }
    }
    // ---- phi-DFT: 1024 virtual units = (bt 512, m-half 2); no LDS/barrier --
    for (int lb = vb; lb < 1024; lb += 768) {
        int bt = lb >> 1, h = lb & 1;
        int iu = tv & 127, mh_loc = tv >> 7;       // 0..1
        int mi0 = (h * 2 + mh_loc) * 8;            // multiples of 8
        float2 acc[8], w[8], st[8];
#pragma unroll
        for (int j = 0; j < 8; ++j) {
            int m = mi0 + j - 15;
            float sy, sx;
            __sincosf(-(float)m * (float)(PI_D / 32.0), &sy, &sx);
            st[j] = make_float2(sx, sy);
            w[j] = make_float2(1.f, 0.f);
            acc[j] = make_float2(0.f, 0.f);
        }
        const float* xrb = xr + (size_t)bt * 8192 + iu;
        const float* xib = xi + (size_t)bt * 8192 + iu;
        for (int p = 0; p < 32; ++p) {
            float a  = xrb[(size_t)p * 128];
            float b  = xib[(size_t)p * 128];
            float a2 = xrb[(size_t)(p + 32) * 128];
            float b2 = xib[(size_t)(p + 32) * 128];
            float sar = a + a2, sai = b + b2;   // even m
            float dar = a - a2, dai = b - b2;   // odd m
#pragma unroll
            for (int j = 0; j < 8; ++j) {
                float ur = (j & 1) ? sar : dar;  // j odd -> m even
                float ui = (j & 1) ? sai : dai;
                acc[j].x += ur * w[j].x - ui * w[j].y;
                acc[j].y += ur * w[j].y + ui * w[j].x;
                float nx = w[j].x * st[j].x - w[j].y * st[j].y;
                w[j].y = w[j].x * st[j].y + w[j].y * st[j].x;
                w[j].x = nx;
            }
        }
        __half2* Fb = F + (size_t)bt * 31 * 128 + iu;
#pragma unroll
        for (int j = 0; j < 8; ++j) {
            int mi = mi0 + j;
            if (mi < 31) Fb[(size_t)mi * 128] = __float22half2_rn(acc[j]);
        }
    }
    gbar(bar, 256);

    // ================= P2: theta-in contraction ============================
    // 496 virtual units (mi 31, b 8, i 2); barriers block-uniform.
    if (bid * 3 < 496) {   // blocks 0..165
        bool act = vb < 496;
        int mi = 0, b = 0, z = 0, m = 0, am = 0;
        if (act) {
            mi = vb % 31;
            int q = vb / 31;
            b = q >> 1; z = q & 1;  // z = i
            m = mi - 15;
            am = m < 0 ? -m : m;
        }
        if (act) {
            for (int idx = tv; idx < 1024; idx += 256) {
                int j = idx >> 6, t = idx & 63;
                float v = 0.f;
                if (j >= am) v = A_in[((size_t)z * 256 + (j * j + j + m)) * 64 + t];
                sm.p2.A[g][j][t] = v;
            }
        }
        __syncthreads();
        int iu_l = tv & 63, th = tv >> 6;
        int iu = z * 64 + iu_l;
        float2 acc[16];
#pragma unroll
        for (int j = 0; j < 16; ++j) acc[j] = make_float2(0.f, 0.f);
        if (act) {
            const __half2* Fb = F + ((size_t)b * 64 * 31 + mi) * 128 + iu;
            for (int tt = 0; tt < 16; ++tt) {
                int t = th * 16 + tt;
                float2 f = __half22float2(Fb[(size_t)t * 31 * 128]);
#pragma unroll
                for (int j = 0; j < 16; ++j) {
                    float a = sm.p2.A[g][j][t];
                    acc[j].x += a * f.x;
                    acc[j].y += a * f.y;
                }
            }
        }
        if (act && th >= 2) {
#pragma unroll
            for (int j = 0; j < 16; ++j) sm.p2.red[g][th - 2][j][iu_l] = acc[j];
        }
        __syncthreads();
        if (act && th < 2) {
#pragma unroll
            for (int j = 0; j < 16; ++j) {
                float2 r = sm.p2.red[g][th][j][iu_l];
                acc[j].x += r.x;
                acc[j].y += r.y;
            }
        }
        __syncthreads();
        if (act && th == 1) {
#pragma unroll
            for (int j = 0; j < 16; ++j) sm.p2.red[g][0][j][iu_l] = acc[j];
        }
        __syncthreads();
        if (act && th == 0) {
#pragma unroll
            for (int j = 0; j < 16; ++j) {
                if (j >= am) {
                    float2 r = sm.p2.red[g][0][j][iu_l];
                    coeffs[((size_t)b * 256 + (j * j + j + m)) * 128 + iu] =
                        __float22half2_rn(
                            make_float2(acc[j].x + r.x, acc[j].y + r.y));
                }
            }
        }
    }
    gbar(bar, 512);

    // ================= P3: channel mix =====================================
    // 1024 virtual units = (bq 2, b-pair 2, k 256); 2 rounds.
    for (int round = 0; round < 2; ++round) {
        if (bid * 3 + round * 768 >= 1024) break;  // uniform per block
        int lb = vb + round * 768;
        bool act = lb < 1024;
        int k = 0, b0 = 0;
        if (act) {
            int y = lb >> 9;                  // bq
            int bh = (lb >> 8) & 1;           // which b-pair
            int bxk = lb & 255;
            k = ((bxk & 7) << 5) + (bxk >> 3);  // XCD-chunked k
            b0 = y * 4 + bh * 2;
            int bb = tv >> 7, iuu = tv & 127;   // tv covers 256 = 2*128
            sm.p3.cs[g][bb][iuu] =
                __half22float2(coeffs[((size_t)(b0 + bb) * 256 + k) * 128 + iuu]);
        }
        __syncthreads();
        if (act && tv < 192) {
            int s = tv >> 6, dp = tv & 63;
            int l = isqrt_k(k);
            float2 acc[2][2];
#pragma unroll
            for (int bb = 0; bb < 2; ++bb) {
                acc[bb][0] = make_float2(0.f, 0.f);
                acc[bb][1] = make_float2(0.f, 0.f);
            }
            const float4* W0 = W + (size_t)(6 * l + s) * 4096 + dp;  // i=0
            const float4* W1 = W0 + (size_t)3 * 4096;                // i=1
            float4 cur[4];
#pragma unroll
            for (int j = 0; j < 4; ++j) cur[j] = W0[(size_t)j * 64];
            for (int gg = 0; gg < 32; ++gg) {
                float4 nxt[4];
                if (gg < 31) {
                    int iu0 = (gg + 1) * 4;
                    const float4* P = (iu0 < 64) ? (W0 + (size_t)iu0 * 64)
                                                 : (W1 + (size_t)(iu0 - 64) * 64);
#pragma unroll
                    for (int j = 0; j < 4; ++j) nxt[j] = P[(size_t)j * 64];
                }
#pragma unroll
                for (int j = 0; j < 4; ++j) {
                    int iu = gg * 4 + j;
                    float2 wr = make_float2(cur[j].x, cur[j].y);
                    float2 wi = make_float2(cur[j].z, cur[j].w);
#pragma unroll
                    for (int bb = 0; bb < 2; ++bb) {
                        float2 cv = sm.p3.cs[g][bb][iu];
                        acc[bb][0].x += cv.x * wr.x - cv.y * wi.x;
                        acc[bb][0].y += cv.x * wi.x + cv.y * wr.x;
                        acc[bb][1].x += cv.x * wr.y - cv.y * wi.y;
                        acc[bb][1].y += cv.x * wi.y + cv.y * wr.y;
                    }
                }
                if (gg < 31) {
#pragma unroll
                    for (int j = 0; j < 4; ++j) cur[j] = nxt[j];
                }
            }
#pragma unroll
            for (int bb = 0; bb < 2; ++bb) {
                size_t o = ((size_t)(b0 + bb) * 256 + k) * 384 + s * 128 + 2 * dp;
                oc[o]     = __float22half2_rn(acc[bb][0]);
                oc[o + 1] = __float22half2_rn(acc[bb][1]);
            }
        }
        __syncthreads();  // protect cs before next round
    }
    gbar(bar, 768);

    // ================= P4: theta expansion + G store + stats ===============
    // 992 virtual units = (mi 31, b 8, t-half 2, sd-half 2); 2 rounds.
    for (int round = 0; round < 2; ++round) {
        if (bid * 3 + round * 768 >= 992) break;  // uniform per block
        int lb = vb + round * 768;
        bool act = lb < 992;
        int mi = 0, b = 0, thalf = 0, shalf = 0, m = 0, am = 0;
        if (act) {
            mi = lb % 31;
            int q = lb / 31;             // 0..31
            b = q >> 2;
            thalf = (q >> 1) & 1;
            shalf = q & 1;
            m = mi - 15;
            am = m < 0 ? -m : m;
            for (int idx = tv; idx < 1536; idx += 256) {
                int s = idx >> 9, j = (idx >> 5) & 15, t = idx & 31;
                float v = 0.f;
                if (j >= am) v = A_out[((size_t)s * 256 + (j * j + j + m)) * 32 + t];
                sm.p4.Ao[g][s][j][t] = v;
            }
        }
        __syncthreads();
        if (act && tv < 192) {
            int sd = shalf * 192 + tv;
            int s = sd >> 7;
            float2 c[16];
#pragma unroll
            for (int j = 0; j < 16; ++j) {
                c[j] = make_float2(0.f, 0.f);
                if (j >= am)
                    c[j] = __half22float2(
                        oc[((size_t)b * 256 + (j * j + j + m)) * 384 + sd]);
            }
            float sq = 0.f, sr = 0.f, si = 0.f;
            int t0 = thalf * 16;
            for (int t = t0; t < t0 + 16; ++t) {
                float fr = 0.f, fi = 0.f;
#pragma unroll
                for (int j = 0; j < 16; ++j) {
                    float a = sm.p4.Ao[g][s][j][t];
                    fr += a * c[j].x;
                    fi += a * c[j].y;
                }
                G[(((size_t)b * 32 + t) * 31 + mi) * 384 + sd] =
                    __float22half2_rn(make_float2(fr, fi));
                sq += fr * fr + fi * fi;
                if (mi == 15) { sr += fr; si += fi; }
            }
            atomicAdd(&ssq[sd], sq);
            if (mi == 15) {
                atomicAdd(&ssr[sd], sr);
                atomicAdd(&ssi[sd], si);
            }
        }
        __syncthreads();  // protect Ao before next round
    }
    gbar(bar, 1024);

    // ================= P5: phi synthesis + BN + gate =======================
    // 1024 virtual units = (bt 256, p-half 2, sd-half 2); 2 rounds.
    for (int round = 0; round < 2; ++round) {
        if (bid * 3 + round * 768 >= 1024) break;  // uniform per block
        int lb = vb + round * 768;
        bool act = lb < 1024;
        int bt = 0, phalf = 0, shalf = 0;
        if (act) {
            bt = lb >> 2;
            phalf = (lb >> 1) & 1;
            shalf = lb & 1;
            if (tv < 248) {
                int p_loc = tv / 31, mi = tv % 31;
                float sy, sx;
                __sincosf((float)(mi - 15) * (float)(phalf * 8 + p_loc)
                              * (float)(PI_D / 16.0), &sy, &sx);
                sm.p5.tab[g][p_loc][mi] = make_float2(sx, sy);
            }
        }
        __syncthreads();
        if (act && tv < 192) {
            int sd = shalf * 192 + tv;
            int s = sd >> 7;
            float2 gg[31];
#pragma unroll
            for (int mi = 0; mi < 31; ++mi)
                gg[mi] = __half22float2(G[((size_t)bt * 31 + mi) * 384 + sd]);
            const float invN = 1.0f / 256.0f;
            float mur = 0.f, mui = 0.f;
            if (s == 0) { mur = ssr[sd] * invN; mui = ssi[sd] * invN; }
            float var = ssq[sd] * invN - (mur * mur + mui * mui);
            float scale = gamma[sd] / sqrtf(var + 1e-5f);
            float br = (s == 0) ? betar[sd] : 0.f;
            float bi = (s == 0) ? betai[sd] : 0.f;
            float bb = bias[sd];
            float* ob = out + (size_t)bt * 32 * 384 + sd;
            for (int p_loc = 0; p_loc < 8; ++p_loc) {
                int p = phalf * 8 + p_loc;
                float fr = 0.f, fi = 0.f, fr2 = 0.f, fi2 = 0.f;
#pragma unroll
                for (int mi = 0; mi < 31; ++mi) {
                    float2 ph = sm.p5.tab[g][p_loc][mi];
                    float tr = gg[mi].x * ph.x - gg[mi].y * ph.y;
                    float ti = gg[mi].x * ph.y + gg[mi].y * ph.x;
                    fr += tr;
                    fi += ti;
                    if (mi & 1) { fr2 += tr; fi2 += ti; }  // m even
                    else        { fr2 -= tr; fi2 -= ti; }  // m odd
                }
                {
                    float yr = (fr - mur) * scale + br;
                    float yi = (fi - mui) * scale + bi;
                    float mag = sqrtf(yr * yr + yi * yi);
                    float f = fmaxf(mag + bb, 0.f) / (mag + 1e-6f);
                    ob[(size_t)p * 384] = yr * f;
                }
                {
                    float yr = (fr2 - mur) * scale + br;
                    float yi = (fi2 - mui) * scale + bi;
                    float mag = sqrtf(yr * yr + yi * yi);
                    float f = fmaxf(mag + bb, 0.f) / (mag + 1e-6f);
                    ob[(size_t)(p + 16) * 384] = yr * f;
                }
            }
        }
        __syncthreads();  // protect tab before next round
    }
}

extern "C" void kernel_launch(void* const* d_in, const int* in_sizes, int n_in,
                              void* d_out, int out_size, void* d_ws, size_t ws_size,
                              hipStream_t stream) {
    const float* xr    = (const float*)d_in[0];
    const float* xi    = (const float*)d_in[1];
    const float* kr    = (const float*)d_in[2];
    const float* ki    = (const float*)d_in[3];
    const float* gamma = (const float*)d_in[4];
    const float* betar = (const float*)d_in[5];
    const float* betai = (const float*)d_in[6];
    const float* bias  = (const float*)d_in[7];
    float* out = (float*)d_out;

    char* ws = (char*)d_ws;
    float*   A_in   = (float*)(ws + OFF_A_IN);
    float*   A_out  = (float*)(ws + OFF_A_OUT);
    float*   stats  = (float*)(ws + OFF_STATS);
    unsigned* bar   = (unsigned*)(ws + OFF_BAR);
    __half2* F      = (__half2*)(ws + OFF_R1);  // aliased: oc after P2
    __half2* oc     = (__half2*)(ws + OFF_R1);
    __half2* coeffs = (__half2*)(ws + OFF_R2);  // aliased: G after P3
    __half2* G      = (__half2*)(ws + OFF_R2);
    float4*  W      = (float4*)(ws + OFF_W);

    hipMemsetAsync(ws + OFF_BAR, 0, 64, stream);  // zero barrier counter
    k_mega<<<256, 768, 0, stream>>>(xr, xi, kr, ki, gamma, betar, betai, bias,
                                    out, A_in, A_out, stats, F, coeffs, oc, G,
                                    W, bar);
}

// Round 11
// 178.297 us; speedup vs baseline: 5.3084x; 2.5186x over previous
//
#include <hip/hip_runtime.h>
#include <hip/hip_fp16.h>
#include <math.h>

// SpinSphericalBlock: separable spin-weighted SHT -> channel mix -> inverse SHT
// -> complex BN (spin0 mean, via Parseval on G) -> magnitude-ReLU gating.
//
// Constants: B=8, RES=64, RES_OUT=32, L=15, SPINS_IN=(0,1), SPINS_OUT=(0,1,2),
// C_IN=64, C_OUT=128, NM=31. Output: out_size=3,145,728 float32 = Re(y),
// (b,t,p,s,d) row-major (established R0-R4).
//
// R27: mega-kernel path (R19-R26) terminated: R26 proved phases in-mega run
// ~2x slower than as separate kernels and are insensitive to occupancy
// (12 waves/CU made it WORSE: 285->378us, VALU-busy-time constant). Revert
// to the proven R18 5-kernel pipeline (179.5us). Measurement from R17/R18:
// K3 ~= 65us (half of kernel time), NOT traffic-bound (R18 halved traffic,
// null) -> latency-bound: 6 waves/CU, serial 32-iter iu-loop of dependent
// L2 loads. R27 changes ONLY K3:
//   * 384 thr = (ih 2, s 3, dp 64): each thread walks its 64-u i-slice ->
//     16 load batches (half the chain), two independent streams per block.
//   * LDS pair-reduction (12KB) combines ih halves; ih=0 writes oc.
//   * ~80 VGPR, launch_bounds(384) (no 2nd-arg squeeze - R22/R23/R24 trap),
//     512 blocks x 6 waves >= 2 blk/CU = 12 waves/CU (2x R18).
// K1/K2/K4/K5 byte-identical to R18 (179.5us verified).
//
//   K1 k_phi_tables: blocks<512: F[bt,m,iu] = sum_p x e^{-im phi_p} (radix-2)
//                    512..626: Wigner tables (fp64 recurrence) + zero stats
//                    627..674: pack weights into float4 W
//   K2 k_theta_in:   coeffs[b,k,iu]= sum_t A_in[i,k,t] F[b,t,m(k),iu]
//   K3 k_mix:        oc[b,k,sd]    = sum_iu coeffs * W[l(k),i,s,u,d]
//   K4 k_theta_out:  G[bt,m,sd]    = sum_l A_out[s,k,t] oc[b,k,sd]  + stats
//   K5 k_synth_final: y = BN(sum_m G e^{+im phi'_p}) -> gate -> Re(y) (radix-2)

#define PI_D 3.14159265358979323846

// ---------------- workspace layout (bytes) ----------------
#define OFF_A_IN    ((size_t)24320)     // 2*256*64 float    = 131072
#define OFF_A_OUT   ((size_t)155648)    // 3*256*32 float    = 98304
#define OFF_STATS   ((size_t)254208)    // 3*384 float       = 4608
#define OFF_R1      ((size_t)260608)    // F fp16 (8.1MB) then oc fp16 (3.1MB)
#define OFF_R2      ((size_t)25426688)  // coeffs fp16 (1MB) then G fp16 (12.2MB)
#define OFF_W       ((size_t)67108864)  // packed weights float4 (6.3MB)

// ln(j!) for j=0..30
__constant__ double LF[31] = {
    0.0, 0.0, 0.6931471805599453, 1.791759469228055, 3.1780538303479458,
    4.787491742782046, 6.579251212010101, 8.525161361065415,
    10.604602902745251, 12.801827480081469, 15.104412573075516,
    17.502307845873887, 19.987214495661885, 22.552163853123425,
    25.19122118273868, 27.89927138384089, 30.671860106080672,
    33.50507345013689, 36.39544520803305, 39.339884187199495,
    42.335616460753485, 45.38013889847691, 48.47118135183523,
    51.60667556776438, 54.78472939811232, 58.00360522298052,
    61.261701761002, 64.55753862700634, 67.88974313718154,
    71.25703896716801, 74.65823634883016};

__device__ inline int isqrt_k(int k) {
    int l = (int)sqrtf((float)k + 0.5f);
    while (l * l > k) --l;
    while ((l + 1) * (l + 1) <= k) ++l;
    return l;
}

// d^l_{m,n}(theta) via seed term (1 exp + 2 log) + exact ratio recurrence.
__device__ double wigner_d_rec(int l, int m, int n, double theta) {
    int an = n < 0 ? -n : n;
    int am = m < 0 ? -m : m;
    if (l < an || l < am) return 0.0;
    int kmin = max(0, n - m), kmax = min(l + n, l - m);
    if (kmax < kmin) return 0.0;
    double cb = cos(0.5 * theta), sb = sin(0.5 * theta);
    double pref = 0.5 * (LF[l + m] + LF[l - m] + LF[l + n] + LF[l - n]);
    double lterm = pref
        - (LF[l + n - kmin] + LF[kmin] + LF[m - n + kmin] + LF[l - m - kmin])
        + (double)(2 * l + n - m - 2 * kmin) * log(cb)
        + (double)(m - n + 2 * kmin) * log(sb);
    double term = exp(lterm);
    if ((m - n + kmin) & 1) term = -term;
    double r = (sb * sb) / (cb * cb);
    double acc = term;
    for (int k = kmin; k < kmax; ++k) {
        term *= -((double)((l + n - k) * (l - m - k)) * r)
                / ((double)((k + 1) * (m - n + k + 1)));
        acc += term;
    }
    return acc;
}

// K1: fused phi-DFT (blocks 0..511) + table generation (512..626)
//     + weight packing (627..674).
__global__ __launch_bounds__(512, 2) void k_phi_tables(const float* __restrict__ xr,
                                                       const float* __restrict__ xi,
                                                       __half2* __restrict__ F,
                                                       float* __restrict__ A_in,
                                                       float* __restrict__ A_out,
                                                       float* __restrict__ stats,
                                                       const float* __restrict__ kr,
                                                       const float* __restrict__ ki,
                                                       float4* __restrict__ W) {
    if (blockIdx.x >= 512) {
        if (blockIdx.x >= 627) {
            // pack kr/ki -> W[lis][u][dp] = (kr2d, kr2d+1, ki2d, ki2d+1)
            int e0 = (blockIdx.x - 627) * 512 + threadIdx.x;
            const float2* kr2 = (const float2*)kr;
            const float2* ki2 = (const float2*)ki;
#pragma unroll
            for (int j = 0; j < 16; ++j) {
                int e = e0 + j * 24576;
                int dp = e & 63, r = e >> 6;   // r = lis*64 + u, r < 6144
                float2 a = kr2[(size_t)r * 64 + dp];
                float2 b = ki2[(size_t)r * 64 + dp];
                W[e] = make_float4(a.x, a.y, b.x, b.y);
            }
            return;
        }
        int idx = (blockIdx.x - 512) * 512 + threadIdx.x;
        if (idx < 32768) {
            int t = idx & 63, k = (idx >> 6) & 255, i = idx >> 14;
            int l = isqrt_k(k);
            int m = k - l * l - l;
            double theta = ((double)t + 0.5) * PI_D / 64.0;
            double w = sin(theta) * (PI_D / 64.0) * (2.0 * PI_D / 64.0);
            double norm = sqrt((2.0 * l + 1.0) / (4.0 * PI_D));
            double d = wigner_d_rec(l, m, -i, theta);
            A_in[idx] = (float)(((m & 1) ? -1.0 : 1.0) * norm * w * d);
            return;
        }
        idx -= 32768;
        if (idx < 24576) {
            int t = idx & 31, k = (idx >> 5) & 255, s = idx >> 13;
            int l = isqrt_k(k);
            int m = k - l * l - l;
            double theta = ((double)t + 0.5) * PI_D / 32.0;
            double norm = sqrt((2.0 * l + 1.0) / (4.0 * PI_D));
            double d = wigner_d_rec(l, m, -s, theta);
            A_out[idx] = (float)(((m & 1) ? -1.0 : 1.0) * norm * d);
            return;
        }
        idx -= 24576;
        if (idx < 1152) stats[idx] = 0.f;
        return;
    }
    int bt = blockIdx.x;
    int iu = threadIdx.x & 127, mh = threadIdx.x >> 7;
    int mi0 = mh * 8;
    float2 acc[8], w[8], st[8];
#pragma unroll
    for (int j = 0; j < 8; ++j) {
        int m = mi0 + j - 15;
        float sy, sx;
        __sincosf(-(float)m * (float)(PI_D / 32.0), &sy, &sx);
        st[j] = make_float2(sx, sy);
        w[j] = make_float2(1.f, 0.f);
        acc[j] = make_float2(0.f, 0.f);
    }
    const float* xrb = xr + (size_t)bt * 8192 + iu;
    const float* xib = xi + (size_t)bt * 8192 + iu;
    for (int p = 0; p < 32; ++p) {
        float a  = xrb[(size_t)p * 128];
        float b  = xib[(size_t)p * 128];
        float a2 = xrb[(size_t)(p + 32) * 128];
        float b2 = xib[(size_t)(p + 32) * 128];
        float sar = a + a2, sai = b + b2;   // for even m
        float dar = a - a2, dai = b - b2;   // for odd m
#pragma unroll
        for (int j = 0; j < 8; ++j) {
            float ur = (j & 1) ? sar : dar;  // j odd -> m even
            float ui = (j & 1) ? sai : dai;
            acc[j].x += ur * w[j].x - ui * w[j].y;
            acc[j].y += ur * w[j].y + ui * w[j].x;
            float nx = w[j].x * st[j].x - w[j].y * st[j].y;
            w[j].y = w[j].x * st[j].y + w[j].y * st[j].x;
            w[j].x = nx;
        }
    }
    __half2* Fb = F + (size_t)bt * 31 * 128 + iu;
#pragma unroll
    for (int j = 0; j < 8; ++j) {
        int mi = mi0 + j;
        if (mi < 31) Fb[(size_t)mi * 128] = __float22half2_rn(acc[j]);
    }
}

// K2: theta contraction. grid (31, 8, 2) = (mi, b, iu-half); 256 threads =
// (iu_l 64) x (th 4). iu-half == spin index i, so only one A_in plane staged.
__global__ __launch_bounds__(256, 4) void k_theta_in(const __half2* __restrict__ F,
                                                     const float* __restrict__ A_in,
                                                     __half2* __restrict__ coeffs) {
    __shared__ float A[16][64];        // 4 KB, zero-padded below |m|
    __shared__ float2 red[2][16][64];  // 16 KB reduction buffer
    int mi = blockIdx.x, b = blockIdx.y, z = blockIdx.z;  // z = i
    int m = mi - 15;
    int am = m < 0 ? -m : m;
    int tid = threadIdx.x;
    for (int idx = tid; idx < 1024; idx += 256) {
        int j = idx >> 6, t = idx & 63;
        float v = 0.f;
        if (j >= am) v = A_in[((size_t)z * 256 + (j * j + j + m)) * 64 + t];
        A[j][t] = v;
    }
    __syncthreads();
    int iu_l = tid & 63, th = tid >> 6;
    int iu = z * 64 + iu_l;
    float2 acc[16];
#pragma unroll
    for (int j = 0; j < 16; ++j) acc[j] = make_float2(0.f, 0.f);
    const __half2* Fb = F + ((size_t)b * 64 * 31 + mi) * 128 + iu;
    for (int tt = 0; tt < 16; ++tt) {
        int t = th * 16 + tt;
        float2 f = __half22float2(Fb[(size_t)t * 31 * 128]);
#pragma unroll
        for (int j = 0; j < 16; ++j) {
            float a = A[j][t];
            acc[j].x += a * f.x;
            acc[j].y += a * f.y;
        }
    }
    if (th >= 2) {
#pragma unroll
        for (int j = 0; j < 16; ++j) red[th - 2][j][iu_l] = acc[j];
    }
    __syncthreads();
    if (th < 2) {
#pragma unroll
        for (int j = 0; j < 16; ++j) {
            float2 r = red[th][j][iu_l];
            acc[j].x += r.x;
            acc[j].y += r.y;
        }
    }
    __syncthreads();
    if (th == 1) {
#pragma unroll
        for (int j = 0; j < 16; ++j) red[0][j][iu_l] = acc[j];
    }
    __syncthreads();
    if (th == 0) {
#pragma unroll
        for (int j = 0; j < 16; ++j) {
            if (j >= am) {
                float2 r = red[0][j][iu_l];
                coeffs[((size_t)b * 256 + (j * j + j + m)) * 128 + iu] =
                    __float22half2_rn(make_float2(acc[j].x + r.x, acc[j].y + r.y));
            }
        }
    }
}

// K3 v5: channel mix, i-split for latency. grid (256, 2) = (k-swizzled, bq);
// 384 threads = (ih 2, s 3, dp 64). Each thread walks its 64-u i-slice
// (16 depth-1-prefetched batches, HALF the R18 chain; the two ih streams are
// independent). LDS pair-reduction combines halves; ih=0 writes oc.
// ~80 VGPR, 512 blocks x 6 waves -> 2 blk/CU = 12 waves/CU (2x R18).
__global__ __launch_bounds__(384) void k_mix(const __half2* __restrict__ coeffs,
                                             const float4* __restrict__ W,
                                             __half2* __restrict__ oc) {
    __shared__ float2 cs[4][128];      // 4 KB
    __shared__ float2 red[192][4][2];  // 12 KB
    int bx = blockIdx.x;
    int k = ((bx & 7) << 5) + (bx >> 3);  // XCD-chunked k
    int b0 = blockIdx.y * 4;
    int tid = threadIdx.x;
    for (int idx = tid; idx < 512; idx += 384) {
        int bb = idx >> 7, iuu = idx & 127;
        cs[bb][iuu] =
            __half22float2(coeffs[((size_t)(b0 + bb) * 256 + k) * 128 + iuu]);
    }
    __syncthreads();
    int ih = tid >= 192 ? 1 : 0;
    int r = tid - ih * 192;
    int s = r >> 6, dp = r & 63;
    int l = isqrt_k(k);
    float2 acc[4][2];
#pragma unroll
    for (int bb = 0; bb < 4; ++bb) {
        acc[bb][0] = make_float2(0.f, 0.f);
        acc[bb][1] = make_float2(0.f, 0.f);
    }
    // W[lis][u][dp], lis = 6l + 3i + s; this thread's slice: i = ih.
    const float4* Wb = W + (size_t)(6 * l + 3 * ih + s) * 4096 + dp;
    float4 cur[4];
#pragma unroll
    for (int j = 0; j < 4; ++j) cur[j] = Wb[(size_t)j * 64];
    for (int g = 0; g < 16; ++g) {
        float4 nxt[4];
        if (g < 15) {
#pragma unroll
            for (int j = 0; j < 4; ++j)
                nxt[j] = Wb[(size_t)((g + 1) * 4 + j) * 64];
        }
#pragma unroll
        for (int j = 0; j < 4; ++j) {
            int iu = ih * 64 + g * 4 + j;
            float2 wr = make_float2(cur[j].x, cur[j].y);
            float2 wi = make_float2(cur[j].z, cur[j].w);
#pragma unroll
            for (int bb = 0; bb < 4; ++bb) {
                float2 cv = cs[bb][iu];
                acc[bb][0].x += cv.x * wr.x - cv.y * wi.x;
                acc[bb][0].y += cv.x * wi.x + cv.y * wr.x;
                acc[bb][1].x += cv.x * wr.y - cv.y * wi.y;
                acc[bb][1].y += cv.x * wi.y + cv.y * wr.y;
            }
        }
        if (g < 15) {
#pragma unroll
            for (int j = 0; j < 4; ++j) cur[j] = nxt[j];
        }
    }
    if (ih == 1) {
#pragma unroll
        for (int bb = 0; bb < 4; ++bb) {
            red[r][bb][0] = acc[bb][0];
            red[r][bb][1] = acc[bb][1];
        }
    }
    __syncthreads();
    if (ih == 0) {
#pragma unroll
        for (int bb = 0; bb < 4; ++bb) {
            float2 r0 = red[r][bb][0];
            float2 r1 = red[r][bb][1];
            size_t o = ((size_t)(b0 + bb) * 256 + k) * 384 + s * 128 + 2 * dp;
            oc[o]     = __float22half2_rn(
                make_float2(acc[bb][0].x + r0.x, acc[bb][0].y + r0.y));
            oc[o + 1] = __float22half2_rn(
                make_float2(acc[bb][1].x + r1.x, acc[bb][1].y + r1.y));
        }
    }
}

// K4: theta expansion + stats. grid (31, 8, 2) = (mi, b, sd-half); 192 threads.
__global__ __launch_bounds__(192, 4) void k_theta_out(const __half2* __restrict__ oc,
                                                      const float* __restrict__ A_out,
                                                      __half2* __restrict__ G,
                                                      float* __restrict__ ssr,
                                                      float* __restrict__ ssi,
                                                      float* __restrict__ ssq) {
    __shared__ float Ao[3][16][32];  // 6KB
    int mi = blockIdx.x, b = blockIdx.y, z = blockIdx.z;
    int m = mi - 15;
    int am = m < 0 ? -m : m;
    int tid = threadIdx.x;
    for (int idx = tid; idx < 1536; idx += 192) {
        int s = idx >> 9, j = (idx >> 5) & 15, t = idx & 31;
        float v = 0.f;
        if (j >= am) v = A_out[((size_t)s * 256 + (j * j + j + m)) * 32 + t];
        Ao[s][j][t] = v;
    }
    __syncthreads();
    int sd = z * 192 + tid;
    int s = sd >> 7;
    float2 c[16];
#pragma unroll
    for (int j = 0; j < 16; ++j) {
        c[j] = make_float2(0.f, 0.f);
        if (j >= am)
            c[j] = __half22float2(oc[((size_t)b * 256 + (j * j + j + m)) * 384 + sd]);
    }
    float sq = 0.f, sr = 0.f, si = 0.f;
    for (int t = 0; t < 32; ++t) {
        float fr = 0.f, fi = 0.f;
#pragma unroll
        for (int j = 0; j < 16; ++j) {
            float a = Ao[s][j][t];
            fr += a * c[j].x;
            fi += a * c[j].y;
        }
        G[(((size_t)b * 32 + t) * 31 + mi) * 384 + sd] =
            __float22half2_rn(make_float2(fr, fi));
        sq += fr * fr + fi * fi;
        if (mi == 15) { sr += fr; si += fi; }
    }
    atomicAdd(&ssq[sd], sq);
    if (mi == 15) {
        atomicAdd(&ssr[sd], sr);
        atomicAdd(&ssi[sd], si);
    }
}

// K5: phi synthesis + BN + gate, radix-2 folded. grid (256 bt, 2 sd-half),
// 192 threads. Rotation state (g[31]+st[31]) in registers; (192,2) caps 256.
__global__ __launch_bounds__(192, 2) void k_synth_final(const __half2* __restrict__ G,
                                                        const float* __restrict__ ssr,
                                                        const float* __restrict__ ssi,
                                                        const float* __restrict__ ssq,
                                                        const float* __restrict__ gamma,
                                                        const float* __restrict__ betar,
                                                        const float* __restrict__ betai,
                                                        const float* __restrict__ bias,
                                                        float* __restrict__ out) {
    int bt = blockIdx.x;
    int sd = blockIdx.y * 192 + threadIdx.x;
    int s = sd >> 7;
    float2 g[31], st[31];
#pragma unroll
    for (int mi = 0; mi < 31; ++mi) {
        g[mi] = __half22float2(G[((size_t)bt * 31 + mi) * 384 + sd]);
        float sy, sx;
        __sincosf((float)(mi - 15) * (float)(PI_D / 16.0), &sy, &sx);
        st[mi] = make_float2(sx, sy);
    }
    const float invN = 1.0f / 256.0f;
    float mur = 0.f, mui = 0.f;
    if (s == 0) { mur = ssr[sd] * invN; mui = ssi[sd] * invN; }
    float var = ssq[sd] * invN - (mur * mur + mui * mui);
    float scale = gamma[sd] / sqrtf(var + 1e-5f);
    float br = (s == 0) ? betar[sd] : 0.f;
    float bi = (s == 0) ? betai[sd] : 0.f;
    float bb = bias[sd];
    float* ob = out + (size_t)bt * 32 * 384 + sd;
    for (int p = 0; p < 16; ++p) {
        float fr = 0.f, fi = 0.f, fr2 = 0.f, fi2 = 0.f;
#pragma unroll
        for (int mi = 0; mi < 31; ++mi) {
            fr += g[mi].x;
            fi += g[mi].y;
            if (mi & 1) { fr2 += g[mi].x; fi2 += g[mi].y; }  // m even
            else        { fr2 -= g[mi].x; fi2 -= g[mi].y; }  // m odd
        }
        {
            float yr = (fr - mur) * scale + br;
            float yi = (fi - mui) * scale + bi;
            float mag = sqrtf(yr * yr + yi * yi);
            float f = fmaxf(mag + bb, 0.f) / (mag + 1e-6f);
            ob[(size_t)p * 384] = yr * f;
        }
        {
            float yr = (fr2 - mur) * scale + br;
            float yi = (fi2 - mui) * scale + bi;
            float mag = sqrtf(yr * yr + yi * yi);
            float f = fmaxf(mag + bb, 0.f) / (mag + 1e-6f);
            ob[(size_t)(p + 16) * 384] = yr * f;
        }
#pragma unroll
        for (int mi = 0; mi < 31; ++mi) {
            float nx = g[mi].x * st[mi].x - g[mi].y * st[mi].y;
            g[mi].y = g[mi].x * st[mi].y + g[mi].y * st[mi].x;
            g[mi].x = nx;
        }
    }
}

extern "C" void kernel_launch(void* const* d_in, const int* in_sizes, int n_in,
                              void* d_out, int out_size, void* d_ws, size_t ws_size,
                              hipStream_t stream) {
    const float* xr    = (const float*)d_in[0];
    const float* xi    = (const float*)d_in[1];
    const float* kr    = (const float*)d_in[2];
    const float* ki    = (const float*)d_in[3];
    const float* gamma = (const float*)d_in[4];
    const float* betar = (const float*)d_in[5];
    const float* betai = (const float*)d_in[6];
    const float* bias  = (const float*)d_in[7];
    float* out = (float*)d_out;

    char* ws = (char*)d_ws;
    float*   A_in   = (float*)(ws + OFF_A_IN);
    float*   A_out  = (float*)(ws + OFF_A_OUT);
    float*   stats  = (float*)(ws + OFF_STATS);
    float*   ssr    = stats;
    float*   ssi    = stats + 384;
    float*   ssq    = stats + 768;
    __half2* F      = (__half2*)(ws + OFF_R1);  // then oc (fp16)
    __half2* oc     = (__half2*)(ws + OFF_R1);
    __half2* coeffs = (__half2*)(ws + OFF_R2);  // then G (fp16)
    __half2* G      = (__half2*)(ws + OFF_R2);
    float4*  W      = (float4*)(ws + OFF_W);

    k_phi_tables<<<675, 512, 0, stream>>>(xr, xi, F, A_in, A_out, stats, kr, ki, W);
    k_theta_in<<<dim3(31, 8, 2), 256, 0, stream>>>(F, A_in, coeffs);
    k_mix<<<dim3(256, 2), 384, 0, stream>>>(coeffs, W, oc);
    k_theta_out<<<dim3(31, 8, 2), 192, 0, stream>>>(oc, A_out, G, ssr, ssi, ssq);
    k_synth_final<<<dim3(256, 2), 192, 0, stream>>>(G, ssr, ssi, ssq,
                                                    gamma, betar, betai, bias, out);
}